// Round 5
// baseline (291.063 us; speedup 1.0000x reference)
//
#include <hip/hip_runtime.h>
#include <math.h>

// Problem constants
#define BATCH 8
#define WAY 5
#define NQ 75
#define NSAMP 80
#define NP 9
#define CCH 640
#define KLEN 192
#define NIMG (BATCH*NSAMP*NP)   // 5760
#define AS 200                  // LDS row stride (bf16 elems) for A tiles
#define NTILES 20               // 640/32 n-tiles
#define NKS 12                  // 192/16 k-steps
#define NFRAG (NTILES*NKS*64)   // 15360 lane-fragments per plane
#define IMGS 8                  // images per conv block (M=128)

typedef short bf16x8 __attribute__((ext_vector_type(8)));
typedef float f32x16 __attribute__((ext_vector_type(16)));

__device__ __forceinline__ void split_bf16(float x, short& hi, short& lo) {
    unsigned xb = __float_as_uint(x);
    hi = (short)(xb >> 16);
    float hf = __uint_as_float(xb & 0xFFFF0000u);
    float r = x - hf;
    lo = (short)(__float_as_uint(r) >> 16);
}

// ---------------------------------------------------------------------------
// Prep: split conv_w (640x192 fp32) into bf16 hi/lo planes, PACKED in MFMA
// B-fragment order: frag f = nt*12+ks, lane l; element j (0..7) is
// w[c = nt*32 + (l&31)][k = ks*16 + (l>>5)*8 + j].
__global__ __launch_bounds__(256) void prep_w_pack(
    const float* __restrict__ w, short* __restrict__ w_hi, short* __restrict__ w_lo)
{
    int i = blockIdx.x * 256 + threadIdx.x;
    if (i < NFRAG) {
        int l = i & 63;
        int frag = i >> 6;
        int ks = frag % NKS;
        int nt = frag / NKS;
        int c = nt * 32 + (l & 31);
        int kb = ks * 16 + (l >> 5) * 8;
        const float* src = w + c * KLEN + kb;
        short h[8], lo[8];
#pragma unroll
        for (int j = 0; j < 8; j++) split_bf16(src[j], h[j], lo[j]);
        *(short4*)(w_hi + (size_t)i * 8)     = make_short4(h[0], h[1], h[2], h[3]);
        *(short4*)(w_hi + (size_t)i * 8 + 4) = make_short4(h[4], h[5], h[6], h[7]);
        *(short4*)(w_lo + (size_t)i * 8)     = make_short4(lo[0], lo[1], lo[2], lo[3]);
        *(short4*)(w_lo + (size_t)i * 8 + 4) = make_short4(lo[4], lo[5], lo[6], lo[7]);
    }
}

// ---------------------------------------------------------------------------
// Kernel 1: per block = 8 patch-images (M=128, 4 M-tiles of 32).
// Wave w owns tiles tau = 10w..10w+9, tau -> (nt = tau>>2, Mt = tau&3);
// 10 consecutive tau span exactly 3 nt quads => 36 B-pair loads per wave,
// ~10 MFMA per pair. bf16 hi/lo 3-term split, fp32 norm epilogue.
__global__ __launch_bounds__(512, 2) void conv_mfma(
    const float* __restrict__ x,      // [NIMG,3,32,32]
    const short* __restrict__ w_hi,   // packed B-fragments
    const short* __restrict__ w_lo,
    float* __restrict__ featn)        // [NIMG][640]
{
    __shared__ short Ah[128 * AS];            // 51.2 KB
    __shared__ short Al[128 * AS];            // 51.2 KB
    __shared__ float ssq_part[8][128];        // 4 KB
    __shared__ float inv_s[128];
    __shared__ float pooled_s[IMGS * CCH];    // 20.5 KB
    __shared__ float invc_s[IMGS];

    const int t = threadIdx.x;
    const int blk = blockIdx.x;

    // ---- load 8 images, rearrange to A[row=img*16+pos][k], split hi/lo
    {
        const float4* xp = (const float4*)(x + (size_t)blk * IMGS * 3072);
#pragma unroll
        for (int i = 0; i < 12; i++) {
            int f = t + i * 512;              // 0..6143 float4s
            int img = f / 768;
            int rem = f - img * 768;
            int ci = rem >> 8;
            int rem2 = rem & 255;
            int h = rem2 >> 3;
            int w4 = (rem2 & 7) << 2;
            int s = ((h >> 3) << 2) + (w4 >> 3);
            int k0 = (ci << 6) + ((h & 7) << 3) + (w4 & 7);
            int row = (img << 4) + s;
            float4 v = xp[f];
            short h0, h1, h2, h3, l0, l1, l2, l3;
            split_bf16(v.x, h0, l0);
            split_bf16(v.y, h1, l1);
            split_bf16(v.z, h2, l2);
            split_bf16(v.w, h3, l3);
            *(short4*)&Ah[row * AS + k0] = make_short4(h0, h1, h2, h3);
            *(short4*)&Al[row * AS + k0] = make_short4(l0, l1, l2, l3);
        }
        // zero ssq partials (8 waves x 128 rows)
        ((float*)ssq_part)[t] = 0.f;
        ((float*)ssq_part)[t + 512] = 0.f;
    }
    __syncthreads();

    const int wv = t >> 6;       // wave 0..7
    const int l  = t & 63;
    const int ln = l & 31;       // MFMA row/col lane
    const int hh = l >> 5;       // k-half
    const int phase = (wv & 1) * 2;           // tau0 % 4  (tau0 = 10*wv)
    const int ntBase = (wv * 10) >> 2;        // first of 3 nt quads

    f32x16 acc[10];
#pragma unroll
    for (int j = 0; j < 10; j++)
#pragma unroll
        for (int r = 0; r < 16; r++) acc[j][r] = 0.f;

    // B pair stream: p = 0..35, ks = p/3, i = p%3, nt = ntBase+i.
    const bf16x8* BH = (const bf16x8*)w_hi + (size_t)ntBase * (NKS * 64) + l;
    const bf16x8* BL = (const bf16x8*)w_lo + (size_t)ntBase * (NKS * 64) + l;
#define BIDX(p) ((((p) % 3) * NKS + ((p) / 3)) * 64)

    bf16x8 bh_r[2], bl_r[2];
    bh_r[0] = BH[BIDX(0)]; bl_r[0] = BL[BIDX(0)];
    bh_r[1] = BH[BIDX(1)]; bl_r[1] = BL[BIDX(1)];

#pragma unroll
    for (int p = 0; p < 36; p++) {
        const int slot = p & 1;
        bf16x8 bh = bh_r[slot];
        bf16x8 blo = bl_r[slot];
        if (p + 2 < 36) {
            bh_r[slot] = BH[BIDX(p + 2)];
            bl_r[slot] = BL[BIDX(p + 2)];
        }
        const int ks = p / 3;
        const int i  = p % 3;
        const int aoff = ks * 16 + hh * 8;
#pragma unroll
        for (int j = 0; j < 10; j++) {
            // tile j active for this nt? ((j+phase)>>2 == i), wave-uniform.
            if (((j + phase) >> 2) == i) {
                int mt = (j + phase) & 3;
                int ao = (mt * 32 + ln) * AS + aoff;
                bf16x8 a_h = *(const bf16x8*)&Ah[ao];
                bf16x8 a_l = *(const bf16x8*)&Al[ao];
                acc[j] = __builtin_amdgcn_mfma_f32_32x32x16_bf16(a_h, bh,  acc[j], 0, 0, 0);
                acc[j] = __builtin_amdgcn_mfma_f32_32x32x16_bf16(a_l, bh,  acc[j], 0, 0, 0);
                acc[j] = __builtin_amdgcn_mfma_f32_32x32x16_bf16(a_h, blo, acc[j], 0, 0, 0);
            }
        }
    }
#undef BIDX

    // ---- ssq per row. C/D layout (32x32): col=ln, rl=(r&3)+8*(r>>2)+4*hh,
    // row = Mt*32 + rl. Accumulate per-wave partials over owned tiles.
#pragma unroll
    for (int j = 0; j < 10; j++) {
        int mt = (j + phase) & 3;
#pragma unroll
        for (int r = 0; r < 16; r++) {
            float v = acc[j][r] * acc[j][r];
            v += __shfl_xor(v, 1);
            v += __shfl_xor(v, 2);
            v += __shfl_xor(v, 4);
            v += __shfl_xor(v, 8);
            v += __shfl_xor(v, 16);
            if (ln == 0) {
                int rl = (r & 3) + ((r >> 2) << 3) + (hh << 2);
                ssq_part[wv][mt * 32 + rl] += v;
            }
        }
    }
    __syncthreads();
    if (t < 128) {
        float s = 0.f;
#pragma unroll
        for (int w = 0; w < 8; w++) s += ssq_part[w][t];
        inv_s[t] = 1.f / fmaxf(sqrtf(s), 1e-12f);
    }
    __syncthreads();

    // ---- pooled[img][c] = sum_pos inv[row]*C[row][c]; img = Mt*2 + (rl>>4)
#pragma unroll
    for (int j = 0; j < 10; j++) {
        int mt = (j + phase) & 3;
        int nt = ntBase + ((j + phase) >> 2);
        int c = nt * 32 + ln;
        float p0 = 0.f, p1 = 0.f;
#pragma unroll
        for (int r = 0; r < 16; r++) {
            int rl = (r & 3) + ((r >> 2) << 3) + (hh << 2);
            float pv = acc[j][r] * inv_s[mt * 32 + rl];
            if (r < 8) p0 += pv; else p1 += pv;
        }
        p0 += __shfl_xor(p0, 32);
        p1 += __shfl_xor(p1, 32);
        if (hh == 0) {
            pooled_s[(mt * 2 + 0) * CCH + c] = p0;
            pooled_s[(mt * 2 + 1) * CCH + c] = p1;
        }
    }
    __syncthreads();

    // ---- per-image row L2-norm (wave wv handles image wv)
    {
        float s = 0.f;
#pragma unroll
        for (int i = 0; i < 10; i++) {
            float pv = pooled_s[wv * CCH + l + 64 * i];
            s += pv * pv;
        }
        s += __shfl_xor(s, 1);
        s += __shfl_xor(s, 2);
        s += __shfl_xor(s, 4);
        s += __shfl_xor(s, 8);
        s += __shfl_xor(s, 16);
        s += __shfl_xor(s, 32);
        if (l == 0) invc_s[wv] = 1.f / fmaxf(sqrtf(s), 1e-12f);
    }
    __syncthreads();
#pragma unroll
    for (int e0 = 0; e0 < 10; e0++) {
        int e = t + e0 * 512;                 // 0..5119
        int im = e / CCH;
        int c2 = e - im * CCH;
        featn[((size_t)blk * IMGS + im) * CCH + c2] = pooled_s[e] * invc_s[im];
    }
}

// ---------------------------------------------------------------------------
// Kernel 2: per (b,m,n): 9x9 sim matrix + greedy row/col-deletion.
__global__ __launch_bounds__(256) void sim_greedy(
    const float* __restrict__ featn,
    float* __restrict__ out)                    // [8][75][5]
{
    __shared__ float rows_s[18][644];
    __shared__ float part_s[81][2];
    __shared__ float sim_s[81];

    const int n = blockIdx.x;
    const int m = blockIdx.y;
    const int b = blockIdx.z;
    const int t = threadIdx.x;

    for (int e = t; e < 18 * 160; e += 256) {
        int r = e / 160;
        int c4 = e - r * 160;
        int g = (r < NP) ? ((b * NSAMP + m) * NP + r)
                         : ((b * NSAMP + WAY + n) * NP + (r - NP));
        *(float4*)&rows_s[r][c4 << 2] = ((const float4*)(featn + (size_t)g * CCH))[c4];
    }
    __syncthreads();

    if (t < 162) {
        int d = t >> 1;
        int half = t & 1;
        int h = d / NP;
        int wq = d - h * NP;
        const float* ph = rows_s[h];
        const float* pq = rows_s[NP + wq];
        float acc = 0.f;
        int base = half * 80;
#pragma unroll 4
        for (int q = 0; q < 80; q++) {
            float4 a = *(const float4*)&ph[(base + q) << 2];
            float4 bb = *(const float4*)&pq[(base + q) << 2];
            acc += a.x * bb.x + a.y * bb.y + a.z * bb.z + a.w * bb.w;
        }
        part_s[d][half] = acc;
    }
    __syncthreads();
    if (t < 81) sim_s[t] = part_s[t][0] + part_s[t][1];
    __syncthreads();

    if (t < 64) {
        float v0 = sim_s[t];
        float v1 = (t < 17) ? sim_s[t + 64] : -3.0e38f;
        int d0r = t / NP, d0c = t - d0r * NP;
        int d1 = t + 64;
        int d1r = d1 / NP, d1c = d1 - d1r * NP;
        unsigned rm = 0x1FF, cm = 0x1FF;
        float total = 0.f, beta = 1.f;
        for (int it = 0; it < NP; it++) {
            float c0 = (((rm >> d0r) & 1u) && ((cm >> d0c) & 1u)) ? v0 : -3.0e38f;
            int i0 = t;
            float c1 = (t < 17 && ((rm >> d1r) & 1u) && ((cm >> d1c) & 1u)) ? v1 : -3.0e38f;
            if (c1 > c0) { c0 = c1; i0 = d1; }
#pragma unroll
            for (int off = 32; off >= 1; off >>= 1) {
                float ov = __shfl_xor(c0, off);
                int oi = __shfl_xor(i0, off);
                if (ov > c0 || (ov == c0 && oi < i0)) { c0 = ov; i0 = oi; }
            }
            total += fmaxf(c0, 0.f) * beta;
            beta *= 0.5f;
            int br = i0 / NP;
            int bc = i0 - br * NP;
            rm &= ~(1u << br);
            cm &= ~(1u << bc);
        }
        if (t == 0) out[((size_t)b * NQ + n) * WAY + m] = total;
    }
}

extern "C" void kernel_launch(void* const* d_in, const int* in_sizes, int n_in,
                              void* d_out, int out_size, void* d_ws, size_t ws_size,
                              hipStream_t stream) {
    const float* data = (const float*)d_in[0];
    const float* conv_w = (const float*)d_in[1];

    float* featn = (float*)d_ws;                           // 14,745,600 B
    short* w_hi = (short*)((char*)d_ws + (size_t)NIMG * CCH * 4);
    short* w_lo = w_hi + (size_t)NFRAG * 8;                // +245,760 B each

    prep_w_pack<<<(NFRAG + 255) / 256, 256, 0, stream>>>(conv_w, w_hi, w_lo);
    conv_mfma<<<NIMG / IMGS, 512, 0, stream>>>(data, w_hi, w_lo, featn);
    dim3 grid(NQ, WAY, BATCH);
    sim_greedy<<<grid, 256, 0, stream>>>(featn, (float*)d_out);
}

// Round 6
// 253.004 us; speedup vs baseline: 1.1504x; 1.1504x over previous
//
#include <hip/hip_runtime.h>
#include <math.h>

// Problem constants
#define BATCH 8
#define WAY 5
#define NQ 75
#define NSAMP 80
#define NP 9
#define CCH 640
#define KLEN 192
#define NIMG (BATCH*NSAMP*NP)   // 5760
#define AS 200                  // LDS row stride (bf16 elems) for A tiles
#define NTILES 20               // 640/32 n-tiles
#define NKS 12                  // 192/16 k-steps
#define NFRAG (NTILES*NKS*64)   // 15360 lane-fragments per plane

typedef short bf16x8 __attribute__((ext_vector_type(8)));
typedef float f32x16 __attribute__((ext_vector_type(16)));

__device__ __forceinline__ void split_bf16(float x, short& hi, short& lo) {
    unsigned xb = __float_as_uint(x);
    hi = (short)(xb >> 16);
    float hf = __uint_as_float(xb & 0xFFFF0000u);
    float r = x - hf;
    lo = (short)(__float_as_uint(r) >> 16);
}

// ---------------------------------------------------------------------------
// Prep: split conv_w (640x192 fp32) into packed bf16 hi/lo B-fragments.
// Fragment f = nt*12+ks, lane l, elem j: w[nt*32+(l&31)][ks*16+(l>>5)*8+j].
// v2: coalesced float4 reads (f = linear over w), scattered 8B writes.
__global__ __launch_bounds__(256) void prep_w_pack(
    const float* __restrict__ w, short* __restrict__ w_hi, short* __restrict__ w_lo)
{
    int f = blockIdx.x * 256 + threadIdx.x;   // float4 index, < 30720
    if (f < CCH * KLEN / 4) {
        int c  = f / 48;
        int kq = f - c * 48;                  // k = kq*4
        int nt = c >> 5;
        int ks = kq >> 2;
        int lane = (c & 31) | (((kq >> 1) & 1) << 5);
        int j = (kq & 1) << 2;
        float4 v = ((const float4*)w)[f];
        short h0, h1, h2, h3, l0, l1, l2, l3;
        split_bf16(v.x, h0, l0);
        split_bf16(v.y, h1, l1);
        split_bf16(v.z, h2, l2);
        split_bf16(v.w, h3, l3);
        size_t dst = ((size_t)(nt * NKS + ks) * 64 + lane) * 8 + j;
        *(short4*)(w_hi + dst) = make_short4(h0, h1, h2, h3);
        *(short4*)(w_lo + dst) = make_short4(l0, l1, l2, l3);
    }
}

// ---------------------------------------------------------------------------
// GEMM inner loop, phase-templated so tile->(mt,rel) indices are compile-time.
// Wave owns tiles tau = 5*wv + j (j=0..4): nt = tau>>1, Mt = tau&1.
// PH = wv&1. ks-outer: A fragments read once per ks, reused across 3 nt.
// B prefetch ring distance 2 (6 pairs in flight).
template<int PH>
__device__ __forceinline__ void gemm_loop(
    const short* __restrict__ Ah, const short* __restrict__ Al,
    const bf16x8* __restrict__ BH, const bf16x8* __restrict__ BL,
    int abase, f32x16 acc[5])
{
    bf16x8 rh[2][3], rl[2][3];
#pragma unroll
    for (int s = 0; s < 2; s++)
#pragma unroll
        for (int r = 0; r < 3; r++) {
            rh[s][r] = BH[(r * NKS + s) * 64];
            rl[s][r] = BL[(r * NKS + s) * 64];
        }
#pragma unroll
    for (int ks = 0; ks < NKS; ks++) {
        const int s = ks & 1;
        bf16x8 aH0 = *(const bf16x8*)&Ah[abase + ks * 16];
        bf16x8 aL0 = *(const bf16x8*)&Al[abase + ks * 16];
        bf16x8 aH1 = *(const bf16x8*)&Ah[abase + 32 * AS + ks * 16];
        bf16x8 aL1 = *(const bf16x8*)&Al[abase + 32 * AS + ks * 16];
        bf16x8 ch[3], cl[3];
#pragma unroll
        for (int r = 0; r < 3; r++) { ch[r] = rh[s][r]; cl[r] = rl[s][r]; }
        if (ks + 2 < NKS) {
#pragma unroll
            for (int r = 0; r < 3; r++) {
                rh[s][r] = BH[(r * NKS + ks + 2) * 64];
                rl[s][r] = BL[(r * NKS + ks + 2) * 64];
            }
        }
#pragma unroll
        for (int j = 0; j < 5; j++) {
            const int mt  = (j + PH) & 1;
            const int rel = (j + PH) >> 1;
            bf16x8 ah = (mt == 0) ? aH0 : aH1;
            bf16x8 al = (mt == 0) ? aL0 : aL1;
            acc[j] = __builtin_amdgcn_mfma_f32_32x32x16_bf16(ah, ch[rel], acc[j], 0, 0, 0);
            acc[j] = __builtin_amdgcn_mfma_f32_32x32x16_bf16(al, ch[rel], acc[j], 0, 0, 0);
            acc[j] = __builtin_amdgcn_mfma_f32_32x32x16_bf16(ah, cl[rel], acc[j], 0, 0, 0);
        }
    }
}

// ---------------------------------------------------------------------------
// Kernel 1: per block = 4 patch-images (M=64 = 2 M-tiles). 8 waves x 5 tiles
// (exactly balanced, 80 acc VGPRs/wave). bf16 hi/lo 3-term split GEMM +
// per-position L2 norm + mean-pool + per-image L2 norm.
__global__ __launch_bounds__(512, 2) void conv_mfma(
    const float* __restrict__ x,      // [NIMG,3,32,32]
    const short* __restrict__ w_hi,   // packed B-fragments
    const short* __restrict__ w_lo,
    float* __restrict__ featn)        // [NIMG][640]
{
    __shared__ short Ah[64 * AS];             // 25.6 KB
    __shared__ short Al[64 * AS];             // 25.6 KB
    __shared__ float ssq_part[8][64];
    __shared__ float inv_s[64];
    __shared__ float pooled_s[4 * CCH];       // 10.2 KB
    __shared__ float rn_part[8];
    __shared__ float invc_s[4];

    const int t = threadIdx.x;
    const int blk = blockIdx.x;

    // ---- load 4 images, rearrange to A[row=img*16+pos][k], split hi/lo
    {
        const float4* xp = (const float4*)(x + (size_t)blk * 4 * 3072);
#pragma unroll
        for (int i = 0; i < 6; i++) {
            int f = t + i * 512;              // 0..3071 float4s
            int img = f / 768;
            int rem = f - img * 768;
            int ci = rem >> 8;
            int rem2 = rem & 255;
            int h = rem2 >> 3;
            int w4 = (rem2 & 7) << 2;
            int s = ((h >> 3) << 2) + (w4 >> 3);
            int k0 = (ci << 6) + ((h & 7) << 3) + (w4 & 7);
            int row = (img << 4) + s;
            float4 v = xp[f];
            short h0, h1, h2, h3, l0, l1, l2, l3;
            split_bf16(v.x, h0, l0);
            split_bf16(v.y, h1, l1);
            split_bf16(v.z, h2, l2);
            split_bf16(v.w, h3, l3);
            *(short4*)&Ah[row * AS + k0] = make_short4(h0, h1, h2, h3);
            *(short4*)&Al[row * AS + k0] = make_short4(l0, l1, l2, l3);
        }
    }
    __syncthreads();

    const int wv = t >> 6;       // wave 0..7
    const int l  = t & 63;
    const int ln = l & 31;       // MFMA col lane
    const int hh = l >> 5;       // k-half
    const int ph = wv & 1;       // phase: tau0 = 5*wv, ph = tau0 & 1
    const int ntBase = (5 * wv) >> 1;

    f32x16 acc[5];
#pragma unroll
    for (int j = 0; j < 5; j++)
#pragma unroll
        for (int r = 0; r < 16; r++) acc[j][r] = 0.f;

    const bf16x8* BH = (const bf16x8*)w_hi + (size_t)ntBase * (NKS * 64) + l;
    const bf16x8* BL = (const bf16x8*)w_lo + (size_t)ntBase * (NKS * 64) + l;
    const int abase = ln * AS + hh * 8;

    if (ph == 0) gemm_loop<0>(Ah, Al, BH, BL, abase, acc);
    else         gemm_loop<1>(Ah, Al, BH, BL, abase, acc);

    // ---- ssq per row. C/D layout (32x32): col=ln, rl=(r&3)+8*(r>>2)+4*hh.
    {
        float rs0[16], rs1[16];
#pragma unroll
        for (int r = 0; r < 16; r++) { rs0[r] = 0.f; rs1[r] = 0.f; }
#pragma unroll
        for (int j = 0; j < 5; j++) {
            const int mt = (j + ph) & 1;      // wave-uniform
            if (mt == 0) {
#pragma unroll
                for (int r = 0; r < 16; r++) rs0[r] += acc[j][r] * acc[j][r];
            } else {
#pragma unroll
                for (int r = 0; r < 16; r++) rs1[r] += acc[j][r] * acc[j][r];
            }
        }
#pragma unroll
        for (int r = 0; r < 16; r++) {
            float v0 = rs0[r], v1 = rs1[r];
            v0 += __shfl_xor(v0, 1);  v1 += __shfl_xor(v1, 1);
            v0 += __shfl_xor(v0, 2);  v1 += __shfl_xor(v1, 2);
            v0 += __shfl_xor(v0, 4);  v1 += __shfl_xor(v1, 4);
            v0 += __shfl_xor(v0, 8);  v1 += __shfl_xor(v1, 8);
            v0 += __shfl_xor(v0, 16); v1 += __shfl_xor(v1, 16);
            if (ln == 0) {
                int rl = (r & 3) + ((r >> 2) << 3) + (hh << 2);
                ssq_part[wv][rl] = v0;
                ssq_part[wv][32 + rl] = v1;
            }
        }
    }
    __syncthreads();
    if (t < 64) {
        float s = 0.f;
#pragma unroll
        for (int w = 0; w < 8; w++) s += ssq_part[w][t];
        inv_s[t] = 1.f / fmaxf(sqrtf(s), 1e-12f);
    }
    __syncthreads();

    // ---- pooled[img][c] = sum_pos inv[row]*C[row][c]; img = mt*2 + (r>=8)
#pragma unroll
    for (int j = 0; j < 5; j++) {
        const int mt  = (j + ph) & 1;
        const int nt  = ntBase + ((j + ph) >> 1);
        const int c   = nt * 32 + ln;
        float p0 = 0.f, p1 = 0.f;
#pragma unroll
        for (int r = 0; r < 16; r++) {
            int rl = (r & 3) + ((r >> 2) << 3) + (hh << 2);
            float pv = acc[j][r] * inv_s[mt * 32 + rl];
            if (r < 8) p0 += pv; else p1 += pv;
        }
        p0 += __shfl_xor(p0, 32);
        p1 += __shfl_xor(p1, 32);
        if (hh == 0) {
            pooled_s[(mt * 2 + 0) * CCH + c] = p0;
            pooled_s[(mt * 2 + 1) * CCH + c] = p1;
        }
    }
    __syncthreads();

    // ---- per-image row L2-norm (2 waves per image)
    {
        int img = wv >> 1;
        int u = ((wv & 1) << 6) + l;
        float s = 0.f;
#pragma unroll
        for (int j = 0; j < 5; j++) {
            float pv = pooled_s[img * CCH + u + 128 * j];
            s += pv * pv;
        }
        s += __shfl_xor(s, 1);
        s += __shfl_xor(s, 2);
        s += __shfl_xor(s, 4);
        s += __shfl_xor(s, 8);
        s += __shfl_xor(s, 16);
        s += __shfl_xor(s, 32);
        if (l == 0) rn_part[wv] = s;
    }
    __syncthreads();
    if (t < 4)
        invc_s[t] = 1.f / fmaxf(sqrtf(rn_part[2 * t] + rn_part[2 * t + 1]), 1e-12f);
    __syncthreads();
#pragma unroll
    for (int e0 = 0; e0 < 5; e0++) {
        int e = t + e0 * 512;
        int im = e / CCH;
        int c2 = e - im * CCH;
        featn[((size_t)blk * 4 + im) * CCH + c2] = pooled_s[e] * invc_s[im];
    }
}

// ---------------------------------------------------------------------------
// Kernel 2 v2: block per (b, n), all 5 m's. Query rows loaded once; support
// streamed per m; 5 greedy problems solved by 5 waves in parallel.
__global__ __launch_bounds__(320) void sim_greedy(
    const float* __restrict__ featn,
    float* __restrict__ out)                    // [8][75][5]
{
    __shared__ float q_s[NP][644];              // 23.2 KB query rows
    __shared__ float s_s[NP][644];              // 23.2 KB support rows (per m)
    __shared__ float part_s[81][2];
    __shared__ float sims_s[WAY][84];

    const int n = blockIdx.x;
    const int b = blockIdx.y;
    const int t = threadIdx.x;

    // load 9 query rows once
    {
        const float* qbase = featn + ((size_t)(b * NSAMP + WAY + n) * NP) * CCH;
        for (int e = t; e < NP * 160; e += 320) {
            int r = e / 160;
            int c4 = e - r * 160;
            *(float4*)&q_s[r][c4 << 2] = ((const float4*)(qbase + (size_t)r * CCH))[c4];
        }
    }

    for (int m = 0; m < WAY; m++) {
        const float* sbase = featn + ((size_t)(b * NSAMP + m) * NP) * CCH;
        for (int e = t; e < NP * 160; e += 320) {
            int r = e / 160;
            int c4 = e - r * 160;
            *(float4*)&s_s[r][c4 << 2] = ((const float4*)(sbase + (size_t)r * CCH))[c4];
        }
        __syncthreads();
        if (t < 162) {
            int d = t >> 1;
            int half = t & 1;
            int h = d / NP;
            int wq = d - h * NP;
            const float* phh = s_s[h];
            const float* pq = q_s[wq];
            float acc = 0.f;
            int base = half * 80;
#pragma unroll 4
            for (int q = 0; q < 80; q++) {
                float4 a  = *(const float4*)&phh[(base + q) << 2];
                float4 bb = *(const float4*)&pq[(base + q) << 2];
                acc += a.x * bb.x + a.y * bb.y + a.z * bb.z + a.w * bb.w;
            }
            part_s[d][half] = acc;
        }
        __syncthreads();
        if (t < 81) sims_s[m][t] = part_s[t][0] + part_s[t][1];
    }
    __syncthreads();

    // 5 waves, wave wv runs greedy for m = wv. Lane l owns sims[l], sims[l+64].
    const int wv = t >> 6;
    const int l = t & 63;
    if (wv < WAY) {
        float v0 = sims_s[wv][l];
        float v1 = (l < 17) ? sims_s[wv][l + 64] : -3.0e38f;
        int d0r = l / NP, d0c = l - d0r * NP;
        int d1 = l + 64;
        int d1r = d1 / NP, d1c = d1 - d1r * NP;
        unsigned rm = 0x1FF, cm = 0x1FF;
        float total = 0.f, beta = 1.f;
        for (int it = 0; it < NP; it++) {
            float c0 = (((rm >> d0r) & 1u) && ((cm >> d0c) & 1u)) ? v0 : -3.0e38f;
            int i0 = l;
            float c1 = (l < 17 && ((rm >> d1r) & 1u) && ((cm >> d1c) & 1u)) ? v1 : -3.0e38f;
            if (c1 > c0) { c0 = c1; i0 = d1; }
#pragma unroll
            for (int off = 32; off >= 1; off >>= 1) {
                float ov = __shfl_xor(c0, off);
                int oi = __shfl_xor(i0, off);
                if (ov > c0 || (ov == c0 && oi < i0)) { c0 = ov; i0 = oi; }
            }
            total += fmaxf(c0, 0.f) * beta;
            beta *= 0.5f;
            int br = i0 / NP;
            int bc = i0 - br * NP;
            rm &= ~(1u << br);
            cm &= ~(1u << bc);
        }
        if (l == 0) out[((size_t)b * NQ + n) * WAY + wv] = total;
    }
}

extern "C" void kernel_launch(void* const* d_in, const int* in_sizes, int n_in,
                              void* d_out, int out_size, void* d_ws, size_t ws_size,
                              hipStream_t stream) {
    const float* data = (const float*)d_in[0];
    const float* conv_w = (const float*)d_in[1];

    float* featn = (float*)d_ws;                           // 14,745,600 B
    short* w_hi = (short*)((char*)d_ws + (size_t)NIMG * CCH * 4);
    short* w_lo = w_hi + (size_t)NFRAG * 8;                // +245,760 B each

    prep_w_pack<<<(CCH * KLEN / 4 + 255) / 256, 256, 0, stream>>>(conv_w, w_hi, w_lo);
    conv_mfma<<<NIMG / 4, 512, 0, stream>>>(data, w_hi, w_lo, featn);
    dim3 grid(NQ, BATCH);
    sim_greedy<<<grid, 320, 0, stream>>>(featn, (float*)d_out);
}